// Round 9
// baseline (212.771 us; speedup 1.0000x reference)
//
#include <hip/hip_runtime.h>
#include <hip/hip_bf16.h>
#include <math.h>

#define B_ 4
#define T_ 2048
#define D_ 128
#define H_ 8
#define BT_ 8192
#define HD_ 1024

typedef __attribute__((ext_vector_type(8))) short bf16x8;
typedef __attribute__((ext_vector_type(4))) float f32x4;

__device__ __forceinline__ short f2bf(float f) {
  union { float f; unsigned u; } v; v.f = f;
  return (short)((v.u + 0x8000u) >> 16);
}

#if __has_builtin(__builtin_amdgcn_exp2f)
#define EXP2F(x) __builtin_amdgcn_exp2f(x)
#else
#define EXP2F(x) exp2f(x)
#endif

#define QSCALE 0.12752040242046492f   // k^-0.5 * log2(e), folded into Q
#define VSCALE 0.29730177875068026f   // k^-0.25, folded into V

// async global->LDS DMA, 16B/lane; LDS dest = wave-uniform base + lane*16
__device__ __forceinline__ void gld16(const short* g, short* l) {
  __builtin_amdgcn_global_load_lds(
      (const __attribute__((address_space(1))) void*)g,
      (__attribute__((address_space(3))) void*)l, 16, 0, 0);
}

__device__ __forceinline__ void wu_transpose_body(
    const float* __restrict__ Wu, short* __restrict__ WuT,
    short* Tt, int kc, int tid)
{
  #pragma unroll 4
  for (int i = tid; i < 4096; i += 256) {
    int kl = i >> 5, n4 = (i & 31) << 2;
    float4 v = *(const float4*)&Wu[(size_t)(kc*128 + kl) * D_ + n4];
    float vv[4] = {v.x, v.y, v.z, v.w};
    #pragma unroll
    for (int j = 0; j < 4; j++) {
      int n = n4 + j;
      Tt[n*128 + (((kl >> 3) ^ (n & 15)) << 3) + (kl & 7)] = f2bf(vv[j]);
    }
  }
  __syncthreads();
  short* dst = WuT + (size_t)kc * 16384;
  #pragma unroll 2
  for (int i = tid; i < 2048; i += 256)
    *(bf16x8*)&dst[i*8] = *(bf16x8*)&Tt[i*8];
}

// ---------------------------------------------------------------------------
// Kernel 0: prep. blocks 0..23: Wq/Wk/Wv -> WT swizzled tile images.
// blocks 24..87: x -> xbf swizzled tile images. blocks 88..95 (only when
// launched with 96 blocks, i.e. ws has room for a standalone WuT): Wu
// transpose -> WuT tile images.
// ---------------------------------------------------------------------------
__global__ __launch_bounds__(256) void prep(
    const float* __restrict__ x, const float* __restrict__ Wq,
    const float* __restrict__ Wk, const float* __restrict__ Wv,
    const float* __restrict__ Wu,
    short* __restrict__ xbf, short* __restrict__ WT, short* __restrict__ WuT)
{
  __shared__ __align__(16) short Tt[128*128];
  const int tid = threadIdx.x;
  const int id = blockIdx.x;
  if (id < 24) {
    const int wsel = id >> 3, nt = id & 7;
    const float* W = (wsel == 0) ? Wq : (wsel == 1) ? Wk : Wv;
    #pragma unroll 4
    for (int i = tid; i < 4096; i += 256) {
      int k = i >> 5, n4 = (i & 31) << 2;
      float4 v = *(const float4*)&W[(size_t)k * HD_ + nt*128 + n4];
      float vv[4] = {v.x, v.y, v.z, v.w};
      #pragma unroll
      for (int j = 0; j < 4; j++) {
        int n = n4 + j;
        Tt[n*128 + (((k >> 3) ^ (n & 15)) << 3) + (k & 7)] = f2bf(vv[j]);
      }
    }
    __syncthreads();
    short* dst = WT + (size_t)id * 16384;
    #pragma unroll 2
    for (int i = tid; i < 2048; i += 256)
      *(bf16x8*)&dst[i*8] = *(bf16x8*)&Tt[i*8];
  } else if (id < 88) {
    const int xb = id - 24;                       // 64 tiles
    const float* xs = x + (size_t)xb * 16384;
    short* dst = xbf + (size_t)xb * 16384;
    #pragma unroll 4
    for (int i = tid; i < 4096; i += 256) {
      float4 v = ((const float4*)xs)[i];
      int row = i >> 5, c = (i & 31) >> 1, half = i & 1;
      short4 p;
      p.x = f2bf(v.x); p.y = f2bf(v.y); p.z = f2bf(v.z); p.w = f2bf(v.w);
      *(short4*)&dst[(row*16 + (c ^ (row & 15)))*8 + half*4] = p;
    }
  } else {
    wu_transpose_body(Wu, WuT, Tt, id - 88, tid);
  }
}

// ---------------------------------------------------------------------------
// Kernel 1: QKV GEMM. grid (64 m, 8 head) = 512 blocks, 2/CU, ONE block-wave.
// x tile staged ONCE per block (A-reuse x3); per-wsel B DMA into Bs, which
// doubles as the epilogue image after MFMA reads complete. Q/K use swapped
// operands (A=W rows) so acc regs span 4 consecutive d -> short4 stores.
// ---------------------------------------------------------------------------
__global__ __launch_bounds__(256, 2) void qkv_proj(
    const short* __restrict__ xbf, const short* __restrict__ WT,
    short* __restrict__ Qw, short* __restrict__ Kw, short* __restrict__ Vw)
{
  __shared__ __align__(16) short As[16384];
  __shared__ __align__(16) short Bs[16384];
  const int tid = threadIdx.x;
  const int w = tid >> 6, lane = tid & 63, quad = lane >> 4, l16 = lane & 15;
  const int m0 = (int)blockIdx.x * 128;
  const int head = (int)blockIdx.y;
  const int so = w*4096 + lane*8;

  {                                               // prologue: A + B(wsel 0)
    const short* asrc = xbf + (size_t)blockIdx.x * 16384;
    const short* bsrc = WT + (size_t)head * 16384;
    #pragma unroll
    for (int cc = 0; cc < 8; cc++) {
      gld16(asrc + so + cc*512, &As[w*4096 + cc*512]);
      gld16(bsrc + so + cc*512, &Bs[w*4096 + cc*512]);
    }
  }

  const int rA0 = (w & 1) * 64, rB0 = (w >> 1) * 64;
  const int b = m0 >> 11, t0g = m0 & 2047;
  const int h = head;

  #pragma unroll 1
  for (int wsel = 0; wsel < 3; wsel++) {
    __syncthreads();                              // B DMA drained at barrier
    // Q/K: A-operand = W rows (d). V: A = x rows (t).
    const short* RA = (wsel <= 1) ? Bs : As;
    const short* RB = (wsel <= 1) ? As : Bs;

    f32x4 acc[4][4];
    #pragma unroll
    for (int a = 0; a < 4; a++)
      #pragma unroll
      for (int bb = 0; bb < 4; bb++) acc[a][bb] = (f32x4){0.f, 0.f, 0.f, 0.f};

    #pragma unroll
    for (int kk = 0; kk < 4; kk++) {
      const int swz = ((kk*4 + quad) ^ l16) << 3;
      bf16x8 af[4], bfv[4];
      #pragma unroll
      for (int ai = 0; ai < 4; ai++) af[ai]  = *(const bf16x8*)&RA[(rA0 + ai*16 + l16)*128 + swz];
      #pragma unroll
      for (int bi = 0; bi < 4; bi++) bfv[bi] = *(const bf16x8*)&RB[(rB0 + bi*16 + l16)*128 + swz];
      #pragma unroll
      for (int ai = 0; ai < 4; ai++)
        #pragma unroll
        for (int bi = 0; bi < 4; bi++)
          acc[ai][bi] = __builtin_amdgcn_mfma_f32_16x16x32_bf16(af[ai], bfv[bi], acc[ai][bi], 0, 0, 0);
    }

    __syncthreads();   // MFMA reads of Bs complete; Bs becomes the image
    if (wsel <= 1) {
      const float sc = wsel ? 1.0f : QSCALE;
      #pragma unroll
      for (int ai = 0; ai < 4; ai++) {
        #pragma unroll
        for (int bi = 0; bi < 4; bi++) {
          const int d0 = rA0 + ai*16 + quad*4;    // 4 consecutive d
          const int t  = rB0 + bi*16 + l16;
          const int tile = t >> 6, tl = t & 63;
          short4 p;
          p.x = f2bf(acc[ai][bi][0] * sc);
          p.y = f2bf(acc[ai][bi][1] * sc);
          p.z = f2bf(acc[ai][bi][2] * sc);
          p.w = f2bf(acc[ai][bi][3] * sc);
          *(short4*)&Bs[tile*8192 + tl*128 + (((d0 >> 3) ^ (tl & 15)) << 3) + (d0 & 7)] = p;
        }
      }
    } else {
      #pragma unroll
      for (int ai = 0; ai < 4; ai++) {
        #pragma unroll
        for (int bi = 0; bi < 4; bi++) {
          const int t0 = rA0 + ai*16 + quad*4;    // 4 consecutive t
          const int d  = rB0 + bi*16 + l16;
          const int tile = t0 >> 6, tl0 = t0 & 63;
          short4 p;
          p.x = f2bf(acc[ai][bi][0] * VSCALE);
          p.y = f2bf(acc[ai][bi][1] * VSCALE);
          p.z = f2bf(acc[ai][bi][2] * VSCALE);
          p.w = f2bf(acc[ai][bi][3] * VSCALE);
          *(short4*)&Bs[tile*8192 + d*64 + (((tl0 >> 3) ^ (d & 7)) << 3) + (tl0 & 7)] = p;
        }
      }
    }
    __syncthreads();                              // image complete

    short* base = ((wsel == 0) ? Qw : (wsel == 1) ? Kw : Vw)
                + (size_t)(b*H_ + h)*262144 + (size_t)t0g*128;
    #pragma unroll 2
    for (int i = tid; i < 2048; i += 256)
      *(bf16x8*)&base[i*8] = *(bf16x8*)&Bs[i*8];

    if (wsel < 2) {
      __syncthreads();                            // copy-out reads done
      const short* bsrc = WT + (size_t)((wsel + 1)*8 + head) * 16384;
      #pragma unroll
      for (int cc = 0; cc < 8; cc++)
        gld16(bsrc + so + cc*512, &Bs[w*4096 + cc*512]);
    }
  }
}

// ---------------------------------------------------------------------------
// Kernel 2: causal flash attention — r11: V read direct from L2 (no LDS).
// r7/r10 scheduling levers were null -> LDS-read pipe is saturated (model:
// 34KB/wave/iter ds_read ~= 45us of the 64). The V tile image in Vw is
// byte-identical to what was staged into Vs, so PV's B-operand reads go
// straight to global (L2/LLC-resident: FETCH stays 24.6MB today). LDS reads
// drop 34->18KB/wave/iter (-47%); V's 16KB moves to the underused L2 pipe
// (~30TB/s aggregate demand < 34.5 ceiling), overlapping with LDS. V staging
// DMA + one barrier per iter removed; LDS 40->24KB. Zero layout/sync change
// on the proven r5 structure -> r6/r8/r9 failure modes don't apply.
// ---------------------------------------------------------------------------
__global__ __launch_bounds__(256, 4) void attn_kernel(
    const short* __restrict__ Qw, const short* __restrict__ Kw,
    const short* __restrict__ Vw, short* __restrict__ attnw)
{
  __shared__ __align__(16) short Ks[8192];        // 64t x 128d swizzled; epi image
  __shared__ __align__(16) short Ps[4096];        // 4 waves x 16x64

  const int tid = threadIdx.x;
  const int id = (int)blockIdx.x;                 // 1024 blocks
  const int xcd = id & 7;
  const int j   = id >> 3;                        // 0..127 within XCD
  const int u   = j & 3;
  const int q   = (j >> 2) & 7;
  const int vv  = (j >> 5) & 3;
  const int slot = u ^ vv;
  const int qi = (slot == 0) ? q : (slot == 1) ? 15 - q
               : (slot == 2) ? 16 + q : 31 - q;
  const int bh = xcd | (u << 3);
  const int b = bh >> 3, h = bh & 7;
  const int w = tid >> 6, lane = tid & 63, quad = lane >> 4, l16 = lane & 15;
  const int rowQ = qi*64 + w*16;

  const short* Qp = Qw + (size_t)bh * 262144;     // swizzled 16KB tiles
  const short* Kp = Kw + (size_t)bh * 262144;
  const short* Vp = Vw + (size_t)bh * 262144;

  bf16x8 qa[4];
  {
    const int tl = (rowQ & 63) + l16;
    const short* qp = Qp + ((size_t)(rowQ >> 6) << 13) + tl*128;
    #pragma unroll
    for (int kk = 0; kk < 4; kk++)
      qa[kk] = *(const bf16x8*)(qp + (((kk*4 + quad) ^ (tl & 15)) << 3));
  }

  f32x4 o[8];
  #pragma unroll
  for (int e = 0; e < 8; e++) o[e] = (f32x4){0,0,0,0};
  float l[4] = {0,0,0,0};

  short* Pw = &Ps[w*1024];
  const int so = w*2048 + lane*8;
  const int nIter = qi + 1;

  for (int it = 0; it < nIter; ++it) {
    if (it) __syncthreads();                      // A: all QK reads of Ks done
    {
      const short* kt = Kp + ((size_t)it << 13);
      #pragma unroll
      for (int cc = 0; cc < 4; cc++)
        gld16(kt + so + cc*512, &Ks[w*2048 + cc*512]);
    }
    __syncthreads();                              // B: K DMA drained

    f32x4 s[4];
    #pragma unroll
    for (int nj = 0; nj < 4; nj++) s[nj] = (f32x4){0,0,0,0};
    __builtin_amdgcn_s_setprio(1);
    #pragma unroll
    for (int kk = 0; kk < 4; kk++) {
      const int swz = ((kk*4 + quad) ^ l16) << 3;
      #pragma unroll
      for (int nj = 0; nj < 4; nj++) {
        bf16x8 kb = *(const bf16x8*)&Ks[(nj*16 + l16)*128 + swz];
        s[nj] = __builtin_amdgcn_mfma_f32_16x16x32_bf16(qa[kk], kb, s[nj], 0, 0, 0);
      }
    }
    __builtin_amdgcn_s_setprio(0);

    if (it < qi) {                                // unmasked tile
      #pragma unroll
      for (int nj = 0; nj < 4; nj++) {
        #pragma unroll
        for (int r = 0; r < 4; r++) {
          float p = EXP2F(s[nj][r]);
          l[r] += p;
          const int row = quad*4 + r, col = nj*16 + l16;
          Pw[row*64 + (((col >> 3) ^ (row & 7)) << 3) + (col & 7)] = f2bf(p);
        }
      }
    } else {                                      // diagonal tile: mask
      const int s0 = it * 64;
      #pragma unroll
      for (int nj = 0; nj < 4; nj++) {
        const int key = s0 + nj*16 + l16;
        #pragma unroll
        for (int r = 0; r < 4; r++) {
          float p = (key > rowQ + quad*4 + r) ? 0.f : EXP2F(s[nj][r]);
          l[r] += p;
          const int row = quad*4 + r, col = nj*16 + l16;
          Pw[row*64 + (((col >> 3) ^ (row & 7)) << 3) + (col & 7)] = f2bf(p);
        }
      }
    }

    // PV: P from per-wave LDS, V DIRECT from global (L2-resident tile image;
    // identical indexing to the former Vs copy).
    const short* vt = Vp + ((size_t)it << 13);
    __builtin_amdgcn_s_setprio(1);
    #pragma unroll
    for (int kk2 = 0; kk2 < 2; kk2++) {
      const int swz = ((kk2*4 + quad) ^ (l16 & 7)) << 3;
      bf16x8 pa = *(bf16x8*)&Pw[l16*64 + swz];
      #pragma unroll
      for (int e = 0; e < 8; e++) {
        bf16x8 vb = *(const bf16x8*)(vt + (e*16 + l16)*64 + swz);
        o[e] = __builtin_amdgcn_mfma_f32_16x16x32_bf16(pa, vb, o[e], 0, 0, 0);
      }
    }
    __builtin_amdgcn_s_setprio(0);
  }

  // epilogue: l-reduce, build 64x128 LDS image in Ks, b128 copy-out
  #pragma unroll
  for (int r = 0; r < 4; r++) {
    float t = l[r];
    t += __shfl_xor(t, 1); t += __shfl_xor(t, 2);
    t += __shfl_xor(t, 4); t += __shfl_xor(t, 8);
    l[r] = 1.0f / t;
  }
  __syncthreads();                                // done reading Ks
  #pragma unroll
  for (int e = 0; e < 8; e++) {
    const int c = e*2 + (l16 >> 3);
    #pragma unroll
    for (int r = 0; r < 4; r++) {
      const int lrow = w*16 + quad*4 + r;         // 0..63
      const int sub = lrow >> 5, r32 = lrow & 31;
      Ks[sub*4096 + r32*128 + ((c ^ (r32 & 15)) << 3) + (l16 & 7)] =
          f2bf(o[e][r] * l[r]);
    }
  }
  __syncthreads();
  const int st0 = b*64 + qi*2;
  #pragma unroll 2
  for (int i = tid; i < 1024; i += 256) {
    const int sub = i >> 9, rem = i & 511;
    short* dst = attnw + ((size_t)(st0 + sub)*8 + h)*4096 + rem*8;
    *(bf16x8*)dst = *(const bf16x8*)&Ks[i*8];
  }
}

// ---------------------------------------------------------------------------
// Kernel 3 (fallback only): Wu -> WuT tile images into dead Kw, after attn.
// ---------------------------------------------------------------------------
__global__ __launch_bounds__(256) void wu_prep(
    const float* __restrict__ Wu, short* __restrict__ WuT)
{
  __shared__ __align__(16) short Tt[128*128];
  wu_transpose_body(Wu, WuT, Tt, blockIdx.x, threadIdx.x);
}

// ---------------------------------------------------------------------------
// Kernel 4: out = attn @ Wu + bu -> fp32. DMA-staged, double-buffered over
// 8 k-chunks, fused bias. grid 512 (m-tile 16), 2 blocks/CU.
// ---------------------------------------------------------------------------
__global__ __launch_bounds__(256, 2) void out_proj(
    const short* __restrict__ attnw, const short* __restrict__ WuT,
    const float* __restrict__ bu, float* __restrict__ out)
{
  __shared__ __align__(16) short As2[2][2048];
  __shared__ __align__(16) short Bs2[2][16384];
  const int tid = threadIdx.x;
  const int w = tid >> 6, lane = tid & 63, quad = lane >> 4, l16 = lane & 15;
  const int m0 = (int)blockIdx.x * 16;
  const int mtile32 = m0 >> 5, half = (m0 >> 4) & 1;

  f32x4 o2[2];
  o2[0] = (f32x4){0,0,0,0}; o2[1] = (f32x4){0,0,0,0};

  {
    const short* ab = attnw + (size_t)(mtile32*8)*4096 + half*2048;
    gld16(ab + w*512 + lane*8, &As2[0][w*512]);
    #pragma unroll
    for (int cc = 0; cc < 8; cc++)
      gld16(WuT + w*4096 + cc*512 + lane*8, &Bs2[0][w*4096 + cc*512]);
  }
  int buf = 0;

  for (int kc = 0; kc < 8; kc++) {
    __syncthreads();
    if (kc < 7) {
      const short* ab = attnw + (size_t)(mtile32*8 + kc + 1)*4096 + half*2048;
      const short* bb = WuT + (size_t)(kc + 1)*16384;
      gld16(ab + w*512 + lane*8, &As2[buf^1][w*512]);
      #pragma unroll
      for (int cc = 0; cc < 8; cc++)
        gld16(bb + w*4096 + cc*512 + lane*8, &Bs2[buf^1][w*4096 + cc*512]);
    }
    const short* as = &As2[buf][0];
    const short* bs = &Bs2[buf][0];
    #pragma unroll
    for (int kk = 0; kk < 4; kk++) {
      const int swz = ((kk*4 + quad) ^ l16) << 3;
      bf16x8 a = *(const bf16x8*)&as[l16*128 + swz];
      #pragma unroll
      for (int e = 0; e < 2; e++) {
        bf16x8 bfr = *(const bf16x8*)&bs[((w*2 + e)*16 + l16)*128 + swz];
        o2[e] = __builtin_amdgcn_mfma_f32_16x16x32_bf16(a, bfr, o2[e], 0, 0, 0);
      }
    }
    buf ^= 1;
  }

  #pragma unroll
  for (int e = 0; e < 2; e++) {
    const int n = (w*2 + e)*16 + l16;
    const float bias = bu[n];
    #pragma unroll
    for (int r = 0; r < 4; r++) {
      const int mm = m0 + quad*4 + r;
      out[(size_t)mm*D_ + n] = o2[e][r] + bias;
    }
  }
}

extern "C" void kernel_launch(void* const* d_in, const int* in_sizes, int n_in,
                              void* d_out, int out_size, void* d_ws, size_t ws_size,
                              hipStream_t stream) {
  (void)in_sizes; (void)n_in; (void)out_size;
  const float* x  = (const float*)d_in[0];
  const float* Wq = (const float*)d_in[1];
  const float* Wk = (const float*)d_in[2];
  const float* Wv = (const float*)d_in[3];
  const float* Wu = (const float*)d_in[4];
  const float* bu = (const float*)d_in[5];
  float* out = (float*)d_out;

  const size_t headElems = (size_t)B_ * H_ * T_ * D_;   // 8,388,608
  short* Qw    = (short*)d_ws;
  short* Kw    = Qw + headElems;
  short* Vw    = Kw + headElems;
  short* attnw = Vw + headElems;                        // 16 MB (tiled images)
  short* xbf = attnw;                                   // prep outputs live in
  short* WT  = attnw + 1048576;                         // not-yet-written attnw

  // WuT: own region past the 64 MB map if ws allows (prep fills it, no
  // wu_prep launch); else dead-Kw reuse after attn (extra launch).
  const bool extraWu = ws_size >= (64ull << 20) + (1ull << 20);
  short* WuT = extraWu ? (short*)((char*)d_ws + (64ull << 20)) : Kw;

  prep<<<dim3(extraWu ? 96 : 88), 256, 0, stream>>>(x, Wq, Wk, Wv, Wu, xbf, WT, WuT);
  qkv_proj<<<dim3(64, 8), 256, 0, stream>>>(xbf, WT, Qw, Kw, Vw);
  attn_kernel<<<dim3(1024), 256, 0, stream>>>(Qw, Kw, Vw, attnw);
  if (!extraWu) wu_prep<<<dim3(8), 256, 0, stream>>>(Wu, WuT);
  out_proj<<<dim3(512), 256, 0, stream>>>(attnw, WuT, bu, out);
}

// Round 10
// 150.319 us; speedup vs baseline: 1.4155x; 1.4155x over previous
//
#include <hip/hip_runtime.h>
#include <hip/hip_bf16.h>
#include <math.h>

#define B_ 4
#define T_ 2048
#define D_ 128
#define H_ 8
#define BT_ 8192
#define HD_ 1024

typedef __attribute__((ext_vector_type(8))) short bf16x8;
typedef __attribute__((ext_vector_type(4))) float f32x4;

__device__ __forceinline__ short f2bf(float f) {
  union { float f; unsigned u; } v; v.f = f;
  return (short)((v.u + 0x8000u) >> 16);
}

#if __has_builtin(__builtin_amdgcn_exp2f)
#define EXP2F(x) __builtin_amdgcn_exp2f(x)
#else
#define EXP2F(x) exp2f(x)
#endif

#define QSCALE 0.12752040242046492f   // k^-0.5 * log2(e), folded into Q
#define VSCALE 0.29730177875068026f   // k^-0.25, folded into V

// async global->LDS DMA, 16B/lane; LDS dest = wave-uniform base + lane*16
__device__ __forceinline__ void gld16(const short* g, short* l) {
  __builtin_amdgcn_global_load_lds(
      (const __attribute__((address_space(1))) void*)g,
      (__attribute__((address_space(3))) void*)l, 16, 0, 0);
}

__device__ __forceinline__ void wu_transpose_body(
    const float* __restrict__ Wu, short* __restrict__ WuT,
    short* Tt, int kc, int tid)
{
  #pragma unroll 4
  for (int i = tid; i < 4096; i += 256) {
    int kl = i >> 5, n4 = (i & 31) << 2;
    float4 v = *(const float4*)&Wu[(size_t)(kc*128 + kl) * D_ + n4];
    float vv[4] = {v.x, v.y, v.z, v.w};
    #pragma unroll
    for (int j = 0; j < 4; j++) {
      int n = n4 + j;
      Tt[n*128 + (((kl >> 3) ^ (n & 15)) << 3) + (kl & 7)] = f2bf(vv[j]);
    }
  }
  __syncthreads();
  short* dst = WuT + (size_t)kc * 16384;
  #pragma unroll 2
  for (int i = tid; i < 2048; i += 256)
    *(bf16x8*)&dst[i*8] = *(bf16x8*)&Tt[i*8];
}

// ---------------------------------------------------------------------------
// Kernel 0: prep. blocks 0..23: Wq/Wk/Wv -> WT swizzled tile images.
// blocks 24..87: x -> xbf swizzled tile images. blocks 88..95 (only when
// launched with 96 blocks, i.e. ws has room for a standalone WuT): Wu
// transpose -> WuT tile images.
// ---------------------------------------------------------------------------
__global__ __launch_bounds__(256) void prep(
    const float* __restrict__ x, const float* __restrict__ Wq,
    const float* __restrict__ Wk, const float* __restrict__ Wv,
    const float* __restrict__ Wu,
    short* __restrict__ xbf, short* __restrict__ WT, short* __restrict__ WuT)
{
  __shared__ __align__(16) short Tt[128*128];
  const int tid = threadIdx.x;
  const int id = blockIdx.x;
  if (id < 24) {
    const int wsel = id >> 3, nt = id & 7;
    const float* W = (wsel == 0) ? Wq : (wsel == 1) ? Wk : Wv;
    #pragma unroll 4
    for (int i = tid; i < 4096; i += 256) {
      int k = i >> 5, n4 = (i & 31) << 2;
      float4 v = *(const float4*)&W[(size_t)k * HD_ + nt*128 + n4];
      float vv[4] = {v.x, v.y, v.z, v.w};
      #pragma unroll
      for (int j = 0; j < 4; j++) {
        int n = n4 + j;
        Tt[n*128 + (((k >> 3) ^ (n & 15)) << 3) + (k & 7)] = f2bf(vv[j]);
      }
    }
    __syncthreads();
    short* dst = WT + (size_t)id * 16384;
    #pragma unroll 2
    for (int i = tid; i < 2048; i += 256)
      *(bf16x8*)&dst[i*8] = *(bf16x8*)&Tt[i*8];
  } else if (id < 88) {
    const int xb = id - 24;                       // 64 tiles
    const float* xs = x + (size_t)xb * 16384;
    short* dst = xbf + (size_t)xb * 16384;
    #pragma unroll 4
    for (int i = tid; i < 4096; i += 256) {
      float4 v = ((const float4*)xs)[i];
      int row = i >> 5, c = (i & 31) >> 1, half = i & 1;
      short4 p;
      p.x = f2bf(v.x); p.y = f2bf(v.y); p.z = f2bf(v.z); p.w = f2bf(v.w);
      *(short4*)&dst[(row*16 + (c ^ (row & 15)))*8 + half*4] = p;
    }
  } else {
    wu_transpose_body(Wu, WuT, Tt, id - 88, tid);
  }
}

// ---------------------------------------------------------------------------
// Kernel 1: QKV GEMM. grid (64 m, 8 head) = 512 blocks, 2/CU, ONE block-wave.
// x tile staged ONCE per block (A-reuse x3); per-wsel B DMA into Bs, which
// doubles as the epilogue image after MFMA reads complete. Q/K use swapped
// operands (A=W rows) so acc regs span 4 consecutive d -> short4 stores.
// ---------------------------------------------------------------------------
__global__ __launch_bounds__(256, 2) void qkv_proj(
    const short* __restrict__ xbf, const short* __restrict__ WT,
    short* __restrict__ Qw, short* __restrict__ Kw, short* __restrict__ Vw)
{
  __shared__ __align__(16) short As[16384];
  __shared__ __align__(16) short Bs[16384];
  const int tid = threadIdx.x;
  const int w = tid >> 6, lane = tid & 63, quad = lane >> 4, l16 = lane & 15;
  const int m0 = (int)blockIdx.x * 128;
  const int head = (int)blockIdx.y;
  const int so = w*4096 + lane*8;

  {                                               // prologue: A + B(wsel 0)
    const short* asrc = xbf + (size_t)blockIdx.x * 16384;
    const short* bsrc = WT + (size_t)head * 16384;
    #pragma unroll
    for (int cc = 0; cc < 8; cc++) {
      gld16(asrc + so + cc*512, &As[w*4096 + cc*512]);
      gld16(bsrc + so + cc*512, &Bs[w*4096 + cc*512]);
    }
  }

  const int rA0 = (w & 1) * 64, rB0 = (w >> 1) * 64;
  const int b = m0 >> 11, t0g = m0 & 2047;
  const int h = head;

  #pragma unroll 1
  for (int wsel = 0; wsel < 3; wsel++) {
    __syncthreads();                              // B DMA drained at barrier
    // Q/K: A-operand = W rows (d). V: A = x rows (t).
    const short* RA = (wsel <= 1) ? Bs : As;
    const short* RB = (wsel <= 1) ? As : Bs;

    f32x4 acc[4][4];
    #pragma unroll
    for (int a = 0; a < 4; a++)
      #pragma unroll
      for (int bb = 0; bb < 4; bb++) acc[a][bb] = (f32x4){0.f, 0.f, 0.f, 0.f};

    #pragma unroll
    for (int kk = 0; kk < 4; kk++) {
      const int swz = ((kk*4 + quad) ^ l16) << 3;
      bf16x8 af[4], bfv[4];
      #pragma unroll
      for (int ai = 0; ai < 4; ai++) af[ai]  = *(const bf16x8*)&RA[(rA0 + ai*16 + l16)*128 + swz];
      #pragma unroll
      for (int bi = 0; bi < 4; bi++) bfv[bi] = *(const bf16x8*)&RB[(rB0 + bi*16 + l16)*128 + swz];
      #pragma unroll
      for (int ai = 0; ai < 4; ai++)
        #pragma unroll
        for (int bi = 0; bi < 4; bi++)
          acc[ai][bi] = __builtin_amdgcn_mfma_f32_16x16x32_bf16(af[ai], bfv[bi], acc[ai][bi], 0, 0, 0);
    }

    __syncthreads();   // MFMA reads of Bs complete; Bs becomes the image
    if (wsel <= 1) {
      const float sc = wsel ? 1.0f : QSCALE;
      #pragma unroll
      for (int ai = 0; ai < 4; ai++) {
        #pragma unroll
        for (int bi = 0; bi < 4; bi++) {
          const int d0 = rA0 + ai*16 + quad*4;    // 4 consecutive d
          const int t  = rB0 + bi*16 + l16;
          const int tile = t >> 6, tl = t & 63;
          short4 p;
          p.x = f2bf(acc[ai][bi][0] * sc);
          p.y = f2bf(acc[ai][bi][1] * sc);
          p.z = f2bf(acc[ai][bi][2] * sc);
          p.w = f2bf(acc[ai][bi][3] * sc);
          *(short4*)&Bs[tile*8192 + tl*128 + (((d0 >> 3) ^ (tl & 15)) << 3) + (d0 & 7)] = p;
        }
      }
    } else {
      #pragma unroll
      for (int ai = 0; ai < 4; ai++) {
        #pragma unroll
        for (int bi = 0; bi < 4; bi++) {
          const int t0 = rA0 + ai*16 + quad*4;    // 4 consecutive t
          const int d  = rB0 + bi*16 + l16;
          const int tile = t0 >> 6, tl0 = t0 & 63;
          short4 p;
          p.x = f2bf(acc[ai][bi][0] * VSCALE);
          p.y = f2bf(acc[ai][bi][1] * VSCALE);
          p.z = f2bf(acc[ai][bi][2] * VSCALE);
          p.w = f2bf(acc[ai][bi][3] * VSCALE);
          *(short4*)&Bs[tile*8192 + d*64 + (((tl0 >> 3) ^ (d & 7)) << 3) + (tl0 & 7)] = p;
        }
      }
    }
    __syncthreads();                              // image complete

    short* base = ((wsel == 0) ? Qw : (wsel == 1) ? Kw : Vw)
                + (size_t)(b*H_ + h)*262144 + (size_t)t0g*128;
    #pragma unroll 2
    for (int i = tid; i < 2048; i += 256)
      *(bf16x8*)&base[i*8] = *(bf16x8*)&Bs[i*8];

    if (wsel < 2) {
      __syncthreads();                            // copy-out reads done
      const short* bsrc = WT + (size_t)((wsel + 1)*8 + head) * 16384;
      #pragma unroll
      for (int cc = 0; cc < 8; cc++)
        gld16(bsrc + so + cc*512, &Bs[w*4096 + cc*512]);
    }
  }
}

// ---------------------------------------------------------------------------
// Kernel 2: causal flash attention — r12: d-split PV on the r5 structure.
// r11 (V from L2) proved V must be LDS-sourced (latency, 125us). The per-wave
// P buffers already tile a complete 64x64 swizzled image in Ps, so PV is
// re-split by d: wave w computes O[all 64 rows x d-strip w*32..+32], reading
// P 8KB + V 4KB instead of P 2KB + V 16KB. LDS reads 34->28KB/wave/iter
// (-18%) at unchanged registers (o[4][2]=32), LDS (40KB), occupancy
// (4 blocks/CU). Cost: one extra barrier/iter (P-write -> PV now crosses
// waves). All address patterns byte-identical in form to r5 (0 conflicts).
// Epilogue: row-sums to Lf[64] in Ps, each wave normalizes its d-strip.
// ---------------------------------------------------------------------------
__global__ __launch_bounds__(256, 4) void attn_kernel(
    const short* __restrict__ Qw, const short* __restrict__ Kw,
    const short* __restrict__ Vw, short* __restrict__ attnw)
{
  __shared__ __align__(16) short Ks[8192];        // 64t x 128d swizzled; epi image
  __shared__ __align__(16) short Vs[8192];        // 128d x 64t swizzled
  __shared__ __align__(16) short Ps[4096];        // 64q x 64k swizzled image; Lf in epi

  const int tid = threadIdx.x;
  const int id = (int)blockIdx.x;                 // 1024 blocks
  const int xcd = id & 7;
  const int j   = id >> 3;                        // 0..127 within XCD
  const int u   = j & 3;
  const int q   = (j >> 2) & 7;
  const int vv  = (j >> 5) & 3;
  const int slot = u ^ vv;
  const int qi = (slot == 0) ? q : (slot == 1) ? 15 - q
               : (slot == 2) ? 16 + q : 31 - q;
  const int bh = xcd | (u << 3);
  const int b = bh >> 3, h = bh & 7;
  const int w = tid >> 6, lane = tid & 63, quad = lane >> 4, l16 = lane & 15;
  const int rowQ = qi*64 + w*16;

  const short* Qp = Qw + (size_t)bh * 262144;     // swizzled 16KB tiles
  const short* Kp = Kw + (size_t)bh * 262144;
  const short* Vp = Vw + (size_t)bh * 262144;

  bf16x8 qa[4];
  {
    const int tl = (rowQ & 63) + l16;
    const short* qp = Qp + ((size_t)(rowQ >> 6) << 13) + tl*128;
    #pragma unroll
    for (int kk = 0; kk < 4; kk++)
      qa[kk] = *(const bf16x8*)(qp + (((kk*4 + quad) ^ (tl & 15)) << 3));
  }

  f32x4 o[4][2];
  #pragma unroll
  for (int m = 0; m < 4; m++) {
    o[m][0] = (f32x4){0,0,0,0};
    o[m][1] = (f32x4){0,0,0,0};
  }
  float l[4] = {0,0,0,0};

  short* Pw = &Ps[w*1024];                        // rows w*16..+16 of P image
  const int so = w*2048 + lane*8;
  const int nIter = qi + 1;

  for (int it = 0; it < nIter; ++it) {
    if (it) __syncthreads();                      // A: prev PV/QK consumers done
    {
      const short* kt = Kp + ((size_t)it << 13);
      const short* vt = Vp + ((size_t)it << 13);
      #pragma unroll
      for (int cc = 0; cc < 4; cc++) {
        gld16(kt + so + cc*512, &Ks[w*2048 + cc*512]);
        gld16(vt + so + cc*512, &Vs[w*2048 + cc*512]);
      }
    }
    __syncthreads();                              // B: DMA drained

    f32x4 s[4];
    #pragma unroll
    for (int nj = 0; nj < 4; nj++) s[nj] = (f32x4){0,0,0,0};
    __builtin_amdgcn_s_setprio(1);
    #pragma unroll
    for (int kk = 0; kk < 4; kk++) {
      const int swz = ((kk*4 + quad) ^ l16) << 3;
      #pragma unroll
      for (int nj = 0; nj < 4; nj++) {
        bf16x8 kb = *(const bf16x8*)&Ks[(nj*16 + l16)*128 + swz];
        s[nj] = __builtin_amdgcn_mfma_f32_16x16x32_bf16(qa[kk], kb, s[nj], 0, 0, 0);
      }
    }
    __builtin_amdgcn_s_setprio(0);

    if (it < qi) {                                // unmasked tile
      #pragma unroll
      for (int nj = 0; nj < 4; nj++) {
        #pragma unroll
        for (int r = 0; r < 4; r++) {
          float p = EXP2F(s[nj][r]);
          l[r] += p;
          const int row = quad*4 + r, col = nj*16 + l16;
          Pw[row*64 + (((col >> 3) ^ (row & 7)) << 3) + (col & 7)] = f2bf(p);
        }
      }
    } else {                                      // diagonal tile: mask
      const int s0 = it * 64;
      #pragma unroll
      for (int nj = 0; nj < 4; nj++) {
        const int key = s0 + nj*16 + l16;
        #pragma unroll
        for (int r = 0; r < 4; r++) {
          float p = (key > rowQ + quad*4 + r) ? 0.f : EXP2F(s[nj][r]);
          l[r] += p;
          const int row = quad*4 + r, col = nj*16 + l16;
          Pw[row*64 + (((col >> 3) ^ (row & 7)) << 3) + (col & 7)] = f2bf(p);
        }
      }
    }
    __syncthreads();                              // C: P image complete

    // PV d-split: wave w owns d-cols w*32..+32; reads full P (8KB) + its
    // V strip (4KB). A = P rows (m*16+l16), B = V rows (d), same swizzle.
    __builtin_amdgcn_s_setprio(1);
    #pragma unroll
    for (int kk2 = 0; kk2 < 2; kk2++) {
      const int sl = ((kk2*4 + quad) ^ (l16 & 7)) << 3;
      bf16x8 vb0 = *(const bf16x8*)&Vs[(w*32 + l16)*64 + sl];
      bf16x8 vb1 = *(const bf16x8*)&Vs[(w*32 + 16 + l16)*64 + sl];
      #pragma unroll
      for (int m = 0; m < 4; m++) {
        bf16x8 pa = *(const bf16x8*)&Ps[(m*16 + l16)*64 + sl];
        o[m][0] = __builtin_amdgcn_mfma_f32_16x16x32_bf16(pa, vb0, o[m][0], 0, 0, 0);
        o[m][1] = __builtin_amdgcn_mfma_f32_16x16x32_bf16(pa, vb1, o[m][1], 0, 0, 0);
      }
    }
    __builtin_amdgcn_s_setprio(0);
  }

  // epilogue: full row-sums -> Lf[64] in Ps; each wave normalizes its strip
  #pragma unroll
  for (int r = 0; r < 4; r++) {
    float t = l[r];
    t += __shfl_xor(t, 1); t += __shfl_xor(t, 2);
    t += __shfl_xor(t, 4); t += __shfl_xor(t, 8);
    l[r] = 1.0f / t;
  }
  __syncthreads();                                // last PV reads of Ps/Vs done
  float* Lf = (float*)Ps;                         // 64 floats
  if (l16 == 0) {
    #pragma unroll
    for (int r = 0; r < 4; r++)
      Lf[w*16 + quad*4 + r] = l[r];
  }
  __syncthreads();
  // build 64x128 image in Ks: wave w writes cols w*32..+32, all rows
  #pragma unroll
  for (int m = 0; m < 4; m++) {
    #pragma unroll
    for (int dt = 0; dt < 2; dt++) {
      const int col = w*32 + dt*16 + l16;
      const int c = col >> 3;
      #pragma unroll
      for (int r = 0; r < 4; r++) {
        const int row = m*16 + quad*4 + r;
        const int sub = row >> 5, r32 = row & 31;
        Ks[sub*4096 + r32*128 + ((c ^ (r32 & 15)) << 3) + (col & 7)] =
            f2bf(o[m][dt][r] * Lf[row]);
      }
    }
  }
  __syncthreads();
  const int st0 = b*64 + qi*2;
  #pragma unroll 2
  for (int i = tid; i < 1024; i += 256) {
    const int sub = i >> 9, rem = i & 511;
    short* dst = attnw + ((size_t)(st0 + sub)*8 + h)*4096 + rem*8;
    *(bf16x8*)dst = *(const bf16x8*)&Ks[i*8];
  }
}

// ---------------------------------------------------------------------------
// Kernel 3 (fallback only): Wu -> WuT tile images into dead Kw, after attn.
// ---------------------------------------------------------------------------
__global__ __launch_bounds__(256) void wu_prep(
    const float* __restrict__ Wu, short* __restrict__ WuT)
{
  __shared__ __align__(16) short Tt[128*128];
  wu_transpose_body(Wu, WuT, Tt, blockIdx.x, threadIdx.x);
}

// ---------------------------------------------------------------------------
// Kernel 4: out = attn @ Wu + bu -> fp32. DMA-staged, double-buffered over
// 8 k-chunks, fused bias. grid 512 (m-tile 16), 2 blocks/CU.
// ---------------------------------------------------------------------------
__global__ __launch_bounds__(256, 2) void out_proj(
    const short* __restrict__ attnw, const short* __restrict__ WuT,
    const float* __restrict__ bu, float* __restrict__ out)
{
  __shared__ __align__(16) short As2[2][2048];
  __shared__ __align__(16) short Bs2[2][16384];
  const int tid = threadIdx.x;
  const int w = tid >> 6, lane = tid & 63, quad = lane >> 4, l16 = lane & 15;
  const int m0 = (int)blockIdx.x * 16;
  const int mtile32 = m0 >> 5, half = (m0 >> 4) & 1;

  f32x4 o2[2];
  o2[0] = (f32x4){0,0,0,0}; o2[1] = (f32x4){0,0,0,0};

  {
    const short* ab = attnw + (size_t)(mtile32*8)*4096 + half*2048;
    gld16(ab + w*512 + lane*8, &As2[0][w*512]);
    #pragma unroll
    for (int cc = 0; cc < 8; cc++)
      gld16(WuT + w*4096 + cc*512 + lane*8, &Bs2[0][w*4096 + cc*512]);
  }
  int buf = 0;

  for (int kc = 0; kc < 8; kc++) {
    __syncthreads();
    if (kc < 7) {
      const short* ab = attnw + (size_t)(mtile32*8 + kc + 1)*4096 + half*2048;
      const short* bb = WuT + (size_t)(kc + 1)*16384;
      gld16(ab + w*512 + lane*8, &As2[buf^1][w*512]);
      #pragma unroll
      for (int cc = 0; cc < 8; cc++)
        gld16(bb + w*4096 + cc*512 + lane*8, &Bs2[buf^1][w*4096 + cc*512]);
    }
    const short* as = &As2[buf][0];
    const short* bs = &Bs2[buf][0];
    #pragma unroll
    for (int kk = 0; kk < 4; kk++) {
      const int swz = ((kk*4 + quad) ^ l16) << 3;
      bf16x8 a = *(const bf16x8*)&as[l16*128 + swz];
      #pragma unroll
      for (int e = 0; e < 2; e++) {
        bf16x8 bfr = *(const bf16x8*)&bs[((w*2 + e)*16 + l16)*128 + swz];
        o2[e] = __builtin_amdgcn_mfma_f32_16x16x32_bf16(a, bfr, o2[e], 0, 0, 0);
      }
    }
    buf ^= 1;
  }

  #pragma unroll
  for (int e = 0; e < 2; e++) {
    const int n = (w*2 + e)*16 + l16;
    const float bias = bu[n];
    #pragma unroll
    for (int r = 0; r < 4; r++) {
      const int mm = m0 + quad*4 + r;
      out[(size_t)mm*D_ + n] = o2[e][r] + bias;
    }
  }
}

extern "C" void kernel_launch(void* const* d_in, const int* in_sizes, int n_in,
                              void* d_out, int out_size, void* d_ws, size_t ws_size,
                              hipStream_t stream) {
  (void)in_sizes; (void)n_in; (void)out_size;
  const float* x  = (const float*)d_in[0];
  const float* Wq = (const float*)d_in[1];
  const float* Wk = (const float*)d_in[2];
  const float* Wv = (const float*)d_in[3];
  const float* Wu = (const float*)d_in[4];
  const float* bu = (const float*)d_in[5];
  float* out = (float*)d_out;

  const size_t headElems = (size_t)B_ * H_ * T_ * D_;   // 8,388,608
  short* Qw    = (short*)d_ws;
  short* Kw    = Qw + headElems;
  short* Vw    = Kw + headElems;
  short* attnw = Vw + headElems;                        // 16 MB (tiled images)
  short* xbf = attnw;                                   // prep outputs live in
  short* WT  = attnw + 1048576;                         // not-yet-written attnw

  // WuT: own region past the 64 MB map if ws allows (prep fills it, no
  // wu_prep launch); else dead-Kw reuse after attn (extra launch).
  const bool extraWu = ws_size >= (64ull << 20) + (1ull << 20);
  short* WuT = extraWu ? (short*)((char*)d_ws + (64ull << 20)) : Kw;

  prep<<<dim3(extraWu ? 96 : 88), 256, 0, stream>>>(x, Wq, Wk, Wv, Wu, xbf, WT, WuT);
  qkv_proj<<<dim3(64, 8), 256, 0, stream>>>(xbf, WT, Qw, Kw, Vw);
  attn_kernel<<<dim3(1024), 256, 0, stream>>>(Qw, Kw, Vw, attnw);
  if (!extraWu) wu_prep<<<dim3(8), 256, 0, stream>>>(Wu, WuT);
  out_proj<<<dim3(512), 256, 0, stream>>>(attnw, WuT, bu, out);
}